// Round 3
// baseline (11472.955 us; speedup 1.0000x reference)
//
#include <hip/hip_runtime.h>

typedef _Float16 f16;
typedef __attribute__((ext_vector_type(8))) _Float16 f16x8;
typedef __attribute__((ext_vector_type(4))) _Float16 f16x4;
typedef __attribute__((ext_vector_type(16))) float f32x16;

#define B_ 128
#define HID_ 1024
#define BH_ (B_ * HID_)   // 131072

// ------- cast + permute x: [B][T][D] f32 -> [T][B][D] f16 -------
__global__ __launch_bounds__(256) void k_cast_x(const float* __restrict__ x,
                                                f16* __restrict__ xf) {
    size_t g = (size_t)blockIdx.x * blockDim.x + threadIdx.x;
    size_t e = g * 4;
    const int d = (int)(e & 255);
    const int t = (int)((e >> 8) & 255);
    const int b = (int)(e >> 16);
    float4 v = ((const float4*)x)[g];
    f16x4 o = {(f16)v.x, (f16)v.y, (f16)v.z, (f16)v.w};
    *(f16x4*)(xf + ((size_t)t * B_ + b) * 256 + d) = o;
}

// ------- pack weights: src[K-span][4096] f32 -> per-WG swizzled f16 blocks -------
// dst element (wg, pcl, k): block = wg*32*Ktot + pcl*Ktot, 16B-chunk swizzle (k>>3)^(pcl&7)
__global__ __launch_bounds__(256) void k_pack(const float* __restrict__ src,
                                              f16* __restrict__ dst,
                                              int Ktot, int koff) {
    __shared__ float tile[64][65];
    const int tx = threadIdx.x & 63, ty = threadIdx.x >> 6;
    const int r0 = blockIdx.y * 64, c0 = blockIdx.x * 64;
    #pragma unroll
    for (int r = ty; r < 64; r += 4)
        tile[r][tx] = src[(size_t)(r0 + r) * 4096 + c0 + tx];
    __syncthreads();
    const int k = koff + r0 + tx;
    #pragma unroll
    for (int rr = ty; rr < 64; rr += 4) {
        const int col = c0 + rr;
        const int g = col >> 10, hg = col & 1023;
        const int wg = hg >> 3, pcl = (g << 3) | (hg & 7);
        size_t off = ((size_t)wg * 32 + pcl) * Ktot + (((k >> 3) ^ (pcl & 7)) << 3) + (k & 7);
        dst[off] = (f16)tile[tx][rr];
    }
}

// ---------------- prep: biases, states, barrier counter ----------------
__global__ __launch_bounds__(256) void k_prep(
    const float* __restrict__ bi1, const float* __restrict__ bh1,
    const float* __restrict__ bi2, const float* __restrict__ bh2,
    const float* __restrict__ h01, const float* __restrict__ h02,
    float* b1, float* b2, f16* h1r, f16* h2b, unsigned int* cnt) {
    int i = blockIdx.x * blockDim.x + threadIdx.x;
    if (i == 0) *cnt = 0u;
    if (i < 4096) { b1[i] = bi1[i] + bh1[i]; b2[i] = bi2[i] + bh2[i]; }
    if (i < BH_) {
        h1r[i] = (f16)h01[i];            // slot 0 = h1 state before step 0
        h2b[BH_ + i] = (f16)h02[i];      // slot 1 = h2 state before step 0
    }
}

// ---------------- persistent: all 257 pipeline stages, weights in LDS ----------------
// 256 WGs x 256 thr. bid<128: layer1 (owns h units bid*8..+8); bid>=128: layer2.
__global__ __launch_bounds__(256, 1) void k_persist(
    const f16* __restrict__ Wp1,   // [128][32][1280] swizzled
    const f16* __restrict__ Wp2,   // [128][32][2048] swizzled
    const f16* __restrict__ xall,  // [256][128][256]
    f16* h1r, f16* h2b,            // [2][128][1024] rings
    float* h2f,                    // [128][1024] final h2 (f32)
    const float* __restrict__ b1, const float* __restrict__ b2,
    const float* __restrict__ c01, const float* __restrict__ c02,
    unsigned int* cnt) {
    __shared__ __align__(16) unsigned char smem[163840];
    f16*   Wl = (f16*)smem;                      // [32][K] (16B-chunk swizzled)
    float* zl = (float*)(smem + 131072);         // [2][128][32] (col-swizzled)

    const int bid = blockIdx.x;
    const int layer = bid >> 7;
    const int wg = bid & 127;
    const int tid = threadIdx.x;
    const int lane = tid & 63, wave = tid >> 6, hl = lane >> 5;

    const int K  = layer ? 2048 : 1280;
    const int K0 = layer ? 1024 : 256;
    const int NCH = K >> 4;                      // 16-k chunks

    // ---- load this WG's weight slice into LDS (swizzle pre-baked) ----
    {
        const f16* Wsrc = layer ? (Wp2 + (size_t)wg * 32 * 2048)
                                : (Wp1 + (size_t)wg * 32 * 1280);
        const int n = 32 * K / 8;                // f16x8 units
        for (int i = tid; i < n; i += 256)
            ((f16x8*)Wl)[i] = ((const f16x8*)Wsrc)[i];
    }

    // ---- per-thread cell state (m = tid&127, units wg*8 + half*4 .. +4) ----
    const int m = tid & 127, half = tid >> 7;
    const int ug0 = wg * 8 + half * 4;
    const float* csrc = layer ? c02 : c01;
    float4 creg = *(const float4*)(csrc + (size_t)m * HID_ + ug0);
    float biasr[4][4];
    {
        const float* bsrc = layer ? b2 : b1;
        #pragma unroll
        for (int g = 0; g < 4; ++g)
            #pragma unroll
            for (int j = 0; j < 4; ++j)
                biasr[g][j] = bsrc[g * HID_ + ug0 + j];
    }
    __syncthreads();

    const int pcl = lane & 31;
    const int swz = pcl & 7;
    f16* hmine = (layer ? h2b : h1r);            // ring this WG writes

    for (int s = 0; s <= 256; ++s) {
        const bool active = layer == 0 ? (s < 256) : (s >= 1);
        if (active) {
            const f16 *A0, *A1;
            int s0, s1;
            if (layer == 0) {
                A0 = xall + (size_t)s * (B_ * 256); s0 = 256;
                A1 = h1r + (size_t)(s & 1) * BH_;   s1 = HID_;
            } else {
                A0 = h1r + (size_t)(s & 1) * BH_;   s0 = HID_;
                A1 = h2b + (size_t)(s & 1) * BH_;   s1 = HID_;
            }
            f32x16 acc[4];
            #pragma unroll
            for (int mt = 0; mt < 4; ++mt)
                #pragma unroll
                for (int r = 0; r < 16; ++r) acc[mt][r] = 0.f;

            // waves split K: wave w takes chunks w, w+4, w+8, ...
            for (int c = wave; c < NCH; c += 4) {
                const int kg = c * 16;
                const f16* Ab; int sa, kloc;
                if (kg < K0) { Ab = A0; sa = s0; kloc = kg; }
                else         { Ab = A1; sa = s1; kloc = kg - K0; }
                const int ic = c * 2 + hl;
                f16x8 bfrag = *(const f16x8*)(Wl + pcl * K + ((ic ^ swz) << 3));
                const f16* ap = Ab + (size_t)pcl * sa + kloc + hl * 8;
                #pragma unroll
                for (int mt = 0; mt < 4; ++mt) {
                    f16x8 afrag = *(const f16x8*)(ap + (size_t)mt * 32 * sa);
                    acc[mt] = __builtin_amdgcn_mfma_f32_32x32x16_f16(afrag, bfrag, acc[mt], 0, 0, 0);
                }
            }

            // z-reduction: waves 0,1 write bufs 0,1; waves 2,3 add
            float* Z = zl + (size_t)(wave & 1) * 4096;
            if (wave < 2) {
                #pragma unroll
                for (int mt = 0; mt < 4; ++mt)
                    #pragma unroll
                    for (int r = 0; r < 16; ++r) {
                        const int row = mt * 32 + (r & 3) + 8 * (r >> 2) + 4 * hl;
                        Z[row * 32 + (pcl ^ (row & 31))] = acc[mt][r];
                    }
            }
            __syncthreads();
            if (wave >= 2) {
                #pragma unroll
                for (int mt = 0; mt < 4; ++mt)
                    #pragma unroll
                    for (int r = 0; r < 16; ++r) {
                        const int row = mt * 32 + (r & 3) + 8 * (r >> 2) + 4 * hl;
                        Z[row * 32 + (pcl ^ (row & 31))] += acc[mt][r];
                    }
            }
            __syncthreads();

            // elementwise: 4 cells per thread
            float zg4[4][4];
            #pragma unroll
            for (int g = 0; g < 4; ++g)
                #pragma unroll
                for (int j = 0; j < 4; ++j) {
                    const int cc = g * 8 + half * 4 + j;
                    const int idx = m * 32 + (cc ^ (m & 31));
                    zg4[g][j] = zl[idx] + zl[4096 + idx] + biasr[g][j];
                }
            f16x4 hout;
            float4 hf;
            #pragma unroll
            for (int j = 0; j < 4; ++j) {
                const float fg = 1.f / (1.f + __expf(-zg4[0][j]));
                const float ig = 1.f / (1.f + __expf(-zg4[1][j]));
                const float gg = 1.f - 2.f / (__expf(2.f * zg4[2][j]) + 1.f);
                const float og = 1.f / (1.f + __expf(-zg4[3][j]));
                float cv = j == 0 ? creg.x : j == 1 ? creg.y : j == 2 ? creg.z : creg.w;
                const float cn = cv * fg + ig * gg;
                if (j == 0) creg.x = cn; else if (j == 1) creg.y = cn;
                else if (j == 2) creg.z = cn; else creg.w = cn;
                const float h = (1.f - 2.f / (__expf(2.f * cn) + 1.f)) * og;
                hout[j] = (f16)h;
                ((float*)&hf)[j] = h;
            }
            *(f16x4*)(hmine + (size_t)((s + 1) & 1) * BH_ + (size_t)m * HID_ + ug0) = hout;
            if (layer == 1 && s == 256)
                *(float4*)(h2f + (size_t)m * HID_ + ug0) = hf;
        }

        // ---- grid barrier (release h-writes, acquire others') ----
        if (s < 256) {
            __syncthreads();                       // all WG stores complete
            if (tid == 0) {
                __threadfence();                   // release: wb L2 to coherence point
                atomicAdd(cnt, 1u);
                const unsigned int target = 256u * (unsigned)(s + 1);
                while (__hip_atomic_load(cnt, __ATOMIC_RELAXED, __HIP_MEMORY_SCOPE_AGENT) < target)
                    __builtin_amdgcn_s_sleep(2);
                __threadfence();                   // acquire: inv L1/L2
            }
            __syncthreads();
        }
    }
}

// ---------------- final: y = h2 @ Wc + bc (fp32) ----------------
__global__ __launch_bounds__(64) void k_final(const float* __restrict__ h2f,
                                              const float* __restrict__ Wc,
                                              const float* __restrict__ bc,
                                              float* __restrict__ y) {
    const int b = blockIdx.x, lane = threadIdx.x;
    float acc[10] = {0, 0, 0, 0, 0, 0, 0, 0, 0, 0};
    for (int k = lane; k < HID_; k += 64) {
        const float h = h2f[b * HID_ + k];
        #pragma unroll
        for (int j = 0; j < 10; ++j) acc[j] = fmaf(h, Wc[k * 10 + j], acc[j]);
    }
    #pragma unroll
    for (int off = 32; off; off >>= 1)
        #pragma unroll
        for (int j = 0; j < 10; ++j) acc[j] += __shfl_down(acc[j], off);
    if (lane == 0) {
        #pragma unroll
        for (int j = 0; j < 10; ++j) y[b * 10 + j] = acc[j] + bc[j];
    }
}

extern "C" void kernel_launch(void* const* d_in, const int* in_sizes, int n_in,
                              void* d_out, int out_size, void* d_ws, size_t ws_size,
                              hipStream_t stream) {
    (void)in_sizes; (void)n_in; (void)out_size; (void)ws_size;
    const float* x   = (const float*)d_in[0];
    const float* h01 = (const float*)d_in[1];
    const float* c01 = (const float*)d_in[2];
    const float* h02 = (const float*)d_in[3];
    const float* c02 = (const float*)d_in[4];
    const float* Wi1 = (const float*)d_in[5];
    const float* Wh1 = (const float*)d_in[6];
    const float* bi1 = (const float*)d_in[7];
    const float* bh1 = (const float*)d_in[8];
    const float* Wi2 = (const float*)d_in[9];
    const float* Wh2 = (const float*)d_in[10];
    const float* bi2 = (const float*)d_in[11];
    const float* bh2 = (const float*)d_in[12];
    const float* Wc  = (const float*)d_in[13];
    const float* bc  = (const float*)d_in[14];
    float* y = (float*)d_out;

    // workspace layout (bytes)
    char* w = (char*)d_ws;
    f16*   xall = (f16*)(w + 0);            // 16,777,216
    f16*   Wp1  = (f16*)(w + 16777216);     // 10,485,760
    f16*   Wp2  = (f16*)(w + 27262976);     // 16,777,216
    f16*   h1r  = (f16*)(w + 44040192);     //    524,288
    f16*   h2b  = (f16*)(w + 44564480);     //    524,288
    float* h2f  = (float*)(w + 45088768);   //    524,288
    float* b1   = (float*)(w + 45613056);   //     16,384
    float* b2   = (float*)(w + 45629440);   //     16,384
    unsigned int* cnt = (unsigned int*)(w + 45645824);

    k_cast_x<<<8192, 256, 0, stream>>>(x, xall);
    k_pack<<<dim3(64, 4),  256, 0, stream>>>(Wi1, Wp1, 1280, 0);
    k_pack<<<dim3(64, 16), 256, 0, stream>>>(Wh1, Wp1, 1280, 256);
    k_pack<<<dim3(64, 16), 256, 0, stream>>>(Wi2, Wp2, 2048, 0);
    k_pack<<<dim3(64, 16), 256, 0, stream>>>(Wh2, Wp2, 2048, 1024);
    k_prep<<<512, 256, 0, stream>>>(bi1, bh1, bi2, bh2, h01, h02, b1, b2, h1r, h2b, cnt);

    k_persist<<<256, 256, 0, stream>>>(Wp1, Wp2, xall, h1r, h2b, h2f, b1, b2, c01, c02, cnt);

    k_final<<<128, 64, 0, stream>>>(h2f, Wc, bc, y);
}

// Round 4
// 7916.534 us; speedup vs baseline: 1.4492x; 1.4492x over previous
//
#include <hip/hip_runtime.h>

typedef _Float16 f16;
typedef __attribute__((ext_vector_type(8))) _Float16 f16x8;
typedef __attribute__((ext_vector_type(4))) _Float16 f16x4;
typedef __attribute__((ext_vector_type(16))) float f32x16;

#define B_ 128
#define HID_ 1024
#define BH_ (B_ * HID_)   // 131072

// ------- cast + permute x: [B][T][D] f32 -> [T][B][D] f16 -------
__global__ __launch_bounds__(256) void k_cast_x(const float* __restrict__ x,
                                                f16* __restrict__ xf) {
    size_t g = (size_t)blockIdx.x * blockDim.x + threadIdx.x;
    size_t e = g * 4;
    const int d = (int)(e & 255);
    const int t = (int)((e >> 8) & 255);
    const int b = (int)(e >> 16);
    float4 v = ((const float4*)x)[g];
    f16x4 o = {(f16)v.x, (f16)v.y, (f16)v.z, (f16)v.w};
    *(f16x4*)(xf + ((size_t)t * B_ + b) * 256 + d) = o;
}

// ------- pack weights: src[K-span][4096] f32 -> per-WG swizzled f16 blocks -------
__global__ __launch_bounds__(256) void k_pack(const float* __restrict__ src,
                                              f16* __restrict__ dst,
                                              int Ktot, int koff) {
    __shared__ float tile[64][65];
    const int tx = threadIdx.x & 63, ty = threadIdx.x >> 6;
    const int r0 = blockIdx.y * 64, c0 = blockIdx.x * 64;
    #pragma unroll
    for (int r = ty; r < 64; r += 4)
        tile[r][tx] = src[(size_t)(r0 + r) * 4096 + c0 + tx];
    __syncthreads();
    const int k = koff + r0 + tx;
    #pragma unroll
    for (int rr = ty; rr < 64; rr += 4) {
        const int col = c0 + rr;
        const int g = col >> 10, hg = col & 1023;
        const int wg = hg >> 3, pcl = (g << 3) | (hg & 7);
        size_t off = ((size_t)wg * 32 + pcl) * Ktot + (((k >> 3) ^ (pcl & 7)) << 3) + (k & 7);
        dst[off] = (f16)tile[tx][rr];
    }
}

// ---------------- prep: biases, states, barrier counter ----------------
__global__ __launch_bounds__(256) void k_prep(
    const float* __restrict__ bi1, const float* __restrict__ bh1,
    const float* __restrict__ bi2, const float* __restrict__ bh2,
    const float* __restrict__ h01, const float* __restrict__ h02,
    float* b1, float* b2, f16* h1r, f16* h2b, unsigned int* cnt) {
    int i = blockIdx.x * blockDim.x + threadIdx.x;
    if (i == 0) *cnt = 0u;
    if (i < 4096) { b1[i] = bi1[i] + bh1[i]; b2[i] = bi2[i] + bh2[i]; }
    if (i < BH_) {
        h1r[i] = (f16)h01[i];            // slot 0 = h1 state before step 0
        h2b[BH_ + i] = (f16)h02[i];      // slot 1 = h2 state before step 0
    }
}

__device__ __forceinline__ void publish8(f16* p, f16x4 v) {
    union { f16x4 h; unsigned long long u; } cv;
    cv.h = v;
    __hip_atomic_store((unsigned long long*)p, cv.u,
                       __ATOMIC_RELAXED, __HIP_MEMORY_SCOPE_AGENT);  // sc1: bypass L2
}

// ---------------- persistent: all 257 pipeline stages, weights in LDS ----------------
__global__ __launch_bounds__(256, 1) void k_persist(
    const f16* __restrict__ Wp1,   // [128][32][1280] swizzled
    const f16* __restrict__ Wp2,   // [128][32][2048] swizzled
    const f16* __restrict__ xall,  // [256][128][256]
    f16* h1r, f16* h2b,            // [2][128][1024] rings
    float* h2f,
    const float* __restrict__ b1, const float* __restrict__ b2,
    const float* __restrict__ c01, const float* __restrict__ c02,
    unsigned int* cnt) {
    __shared__ __align__(16) unsigned char smem[163840];
    f16*   Wl = (f16*)smem;                      // [32][K] (16B-chunk swizzled)
    float* zl = (float*)(smem + 131072);         // [2][128][32] (col-swizzled)

    const int bid = blockIdx.x;
    const int layer = bid >> 7;
    const int wg = bid & 127;
    const int tid = threadIdx.x;
    const int lane = tid & 63, wave = tid >> 6, hl = lane >> 5;
    const int K = layer ? 2048 : 1280;

    {   // weight slice -> LDS (swizzle pre-baked)
        const f16* Wsrc = layer ? (Wp2 + (size_t)wg * 32 * 2048)
                                : (Wp1 + (size_t)wg * 32 * 1280);
        const int n = 32 * K / 8;
        for (int i = tid; i < n; i += 256)
            ((f16x8*)Wl)[i] = ((const f16x8*)Wsrc)[i];
    }

    const int m = tid & 127, half = tid >> 7;
    const int ug0 = wg * 8 + half * 4;
    const float* csrc = layer ? c02 : c01;
    float4 creg = *(const float4*)(csrc + (size_t)m * HID_ + ug0);
    float biasr[4][4];
    {
        const float* bsrc = layer ? b2 : b1;
        #pragma unroll
        for (int g = 0; g < 4; ++g)
            #pragma unroll
            for (int j = 0; j < 4; ++j)
                biasr[g][j] = bsrc[g * HID_ + ug0 + j];
    }
    __syncthreads();

    const int pcl = lane & 31;
    const int swz = pcl & 7;
    f16* hmine = (layer ? h2b : h1r);

    f32x16 acc[4];
    #pragma unroll
    for (int mt = 0; mt < 4; ++mt)
        #pragma unroll
        for (int r = 0; r < 16; ++r) acc[mt][r] = 0.f;

    // prologue: L1 prefetch x-part for step 0
    if (layer == 0) {
        const f16* A0n = xall;                       // step 0
        for (int c = wave; c < 16; c += 4) {
            const int ic = c * 2 + hl;
            f16x8 bfrag = *(const f16x8*)(Wl + pcl * 1280 + ((ic ^ swz) << 3));
            const f16* ap = A0n + (size_t)pcl * 256 + c * 16 + hl * 8;
            #pragma unroll
            for (int mt = 0; mt < 4; ++mt) {
                f16x8 afrag = *(const f16x8*)(ap + (size_t)mt * 32 * 256);
                acc[mt] = __builtin_amdgcn_mfma_f32_32x32x16_f16(afrag, bfrag, acc[mt], 0, 0, 0);
            }
        }
    }

    for (int s = 0; s <= 256; ++s) {
        const bool active = layer == 0 ? (s < 256) : (s >= 1);
        if (active) {
            // -------- h-dependent MFMA chunks --------
            if (layer == 0) {
                const f16* A1 = h1r + (size_t)(s & 1) * BH_;
                for (int c = 16 + wave; c < 80; c += 4) {
                    const int ic = c * 2 + hl;
                    f16x8 bfrag = *(const f16x8*)(Wl + pcl * 1280 + ((ic ^ swz) << 3));
                    const f16* ap = A1 + (size_t)pcl * HID_ + (c * 16 - 256) + hl * 8;
                    #pragma unroll
                    for (int mt = 0; mt < 4; ++mt) {
                        f16x8 afrag = *(const f16x8*)(ap + (size_t)mt * 32 * HID_);
                        acc[mt] = __builtin_amdgcn_mfma_f32_32x32x16_f16(afrag, bfrag, acc[mt], 0, 0, 0);
                    }
                }
            } else {
                const f16* A0 = h1r + (size_t)(s & 1) * BH_;
                const f16* A1 = h2b + (size_t)(s & 1) * BH_;
                for (int c = wave; c < 128; c += 4) {
                    const f16* Ab = (c < 64) ? A0 : A1;
                    const int kloc = (c & 63) * 16;
                    const int ic = c * 2 + hl;
                    f16x8 bfrag = *(const f16x8*)(Wl + pcl * 2048 + ((ic ^ swz) << 3));
                    const f16* ap = Ab + (size_t)pcl * HID_ + kloc + hl * 8;
                    #pragma unroll
                    for (int mt = 0; mt < 4; ++mt) {
                        f16x8 afrag = *(const f16x8*)(ap + (size_t)mt * 32 * HID_);
                        acc[mt] = __builtin_amdgcn_mfma_f32_32x32x16_f16(afrag, bfrag, acc[mt], 0, 0, 0);
                    }
                }
            }

            // -------- z-reduction in LDS --------
            float* Z = zl + (size_t)(wave & 1) * 4096;
            if (wave < 2) {
                #pragma unroll
                for (int mt = 0; mt < 4; ++mt)
                    #pragma unroll
                    for (int r = 0; r < 16; ++r) {
                        const int row = mt * 32 + (r & 3) + 8 * (r >> 2) + 4 * hl;
                        Z[row * 32 + (pcl ^ (row & 31))] = acc[mt][r];
                    }
            }
            __syncthreads();
            if (wave >= 2) {
                #pragma unroll
                for (int mt = 0; mt < 4; ++mt)
                    #pragma unroll
                    for (int r = 0; r < 16; ++r) {
                        const int row = mt * 32 + (r & 3) + 8 * (r >> 2) + 4 * hl;
                        Z[row * 32 + (pcl ^ (row & 31))] += acc[mt][r];
                    }
            }
            __syncthreads();

            // -------- elementwise + publish --------
            float zg4[4][4];
            #pragma unroll
            for (int g = 0; g < 4; ++g)
                #pragma unroll
                for (int j = 0; j < 4; ++j) {
                    const int cc = g * 8 + half * 4 + j;
                    const int idx = m * 32 + (cc ^ (m & 31));
                    zg4[g][j] = zl[idx] + zl[4096 + idx] + biasr[g][j];
                }
            f16x4 hout;
            float4 hf;
            #pragma unroll
            for (int j = 0; j < 4; ++j) {
                const float fg = 1.f / (1.f + __expf(-zg4[0][j]));
                const float ig = 1.f / (1.f + __expf(-zg4[1][j]));
                const float gg = 1.f - 2.f / (__expf(2.f * zg4[2][j]) + 1.f);
                const float og = 1.f / (1.f + __expf(-zg4[3][j]));
                float cv = j == 0 ? creg.x : j == 1 ? creg.y : j == 2 ? creg.z : creg.w;
                const float cn = cv * fg + ig * gg;
                if (j == 0) creg.x = cn; else if (j == 1) creg.y = cn;
                else if (j == 2) creg.z = cn; else creg.w = cn;
                const float h = (1.f - 2.f / (__expf(2.f * cn) + 1.f)) * og;
                hout[j] = (f16)h;
                ((float*)&hf)[j] = h;
            }
            publish8(hmine + (size_t)((s + 1) & 1) * BH_ + (size_t)m * HID_ + ug0, hout);
            if (layer == 1 && s == 256)
                *(float4*)(h2f + (size_t)m * HID_ + ug0) = hf;
        }

        // -------- cheap grid barrier: no L2 writeback --------
        if (s < 256) {
            asm volatile("s_waitcnt vmcnt(0)" ::: "memory");   // this wave's sc1 stores at L3
            __syncthreads();                                   // all waves' stores retired
            if (tid == 0)
                __hip_atomic_fetch_add(cnt, 1u, __ATOMIC_RELAXED, __HIP_MEMORY_SCOPE_AGENT);

            // overlap: clear acc; L1 prefetches next step's x-projection during the wait
            #pragma unroll
            for (int mt = 0; mt < 4; ++mt)
                #pragma unroll
                for (int r = 0; r < 16; ++r) acc[mt][r] = 0.f;
            if (layer == 0 && s + 1 < 256) {
                const f16* A0n = xall + (size_t)(s + 1) * (B_ * 256);
                for (int c = wave; c < 16; c += 4) {
                    const int ic = c * 2 + hl;
                    f16x8 bfrag = *(const f16x8*)(Wl + pcl * 1280 + ((ic ^ swz) << 3));
                    const f16* ap = A0n + (size_t)pcl * 256 + c * 16 + hl * 8;
                    #pragma unroll
                    for (int mt = 0; mt < 4; ++mt) {
                        f16x8 afrag = *(const f16x8*)(ap + (size_t)mt * 32 * 256);
                        acc[mt] = __builtin_amdgcn_mfma_f32_32x32x16_f16(afrag, bfrag, acc[mt], 0, 0, 0);
                    }
                }
            }

            if (tid == 0) {
                const unsigned int target = 256u * (unsigned)(s + 1);
                while (__hip_atomic_load(cnt, __ATOMIC_RELAXED, __HIP_MEMORY_SCOPE_AGENT) < target)
                    __builtin_amdgcn_s_sleep(8);
                __builtin_amdgcn_fence(__ATOMIC_ACQUIRE, "agent");  // buffer_inv, no wbl2
            }
            __syncthreads();
        }
    }
}

// ---------------- final: y = h2 @ Wc + bc (fp32) ----------------
__global__ __launch_bounds__(64) void k_final(const float* __restrict__ h2f,
                                              const float* __restrict__ Wc,
                                              const float* __restrict__ bc,
                                              float* __restrict__ y) {
    const int b = blockIdx.x, lane = threadIdx.x;
    float acc[10] = {0, 0, 0, 0, 0, 0, 0, 0, 0, 0};
    for (int k = lane; k < HID_; k += 64) {
        const float h = h2f[b * HID_ + k];
        #pragma unroll
        for (int j = 0; j < 10; ++j) acc[j] = fmaf(h, Wc[k * 10 + j], acc[j]);
    }
    #pragma unroll
    for (int off = 32; off; off >>= 1)
        #pragma unroll
        for (int j = 0; j < 10; ++j) acc[j] += __shfl_down(acc[j], off);
    if (lane == 0) {
        #pragma unroll
        for (int j = 0; j < 10; ++j) y[b * 10 + j] = acc[j] + bc[j];
    }
}

extern "C" void kernel_launch(void* const* d_in, const int* in_sizes, int n_in,
                              void* d_out, int out_size, void* d_ws, size_t ws_size,
                              hipStream_t stream) {
    (void)in_sizes; (void)n_in; (void)out_size; (void)ws_size;
    const float* x   = (const float*)d_in[0];
    const float* h01 = (const float*)d_in[1];
    const float* c01 = (const float*)d_in[2];
    const float* h02 = (const float*)d_in[3];
    const float* c02 = (const float*)d_in[4];
    const float* Wi1 = (const float*)d_in[5];
    const float* Wh1 = (const float*)d_in[6];
    const float* bi1 = (const float*)d_in[7];
    const float* bh1 = (const float*)d_in[8];
    const float* Wi2 = (const float*)d_in[9];
    const float* Wh2 = (const float*)d_in[10];
    const float* bi2 = (const float*)d_in[11];
    const float* bh2 = (const float*)d_in[12];
    const float* Wc  = (const float*)d_in[13];
    const float* bc  = (const float*)d_in[14];
    float* y = (float*)d_out;

    char* w = (char*)d_ws;
    f16*   xall = (f16*)(w + 0);            // 16,777,216
    f16*   Wp1  = (f16*)(w + 16777216);     // 10,485,760
    f16*   Wp2  = (f16*)(w + 27262976);     // 16,777,216
    f16*   h1r  = (f16*)(w + 44040192);     //    524,288
    f16*   h2b  = (f16*)(w + 44564480);     //    524,288
    float* h2f  = (float*)(w + 45088768);   //    524,288
    float* b1   = (float*)(w + 45613056);   //     16,384
    float* b2   = (float*)(w + 45629440);   //     16,384
    unsigned int* cnt = (unsigned int*)(w + 45645824);

    k_cast_x<<<8192, 256, 0, stream>>>(x, xall);
    k_pack<<<dim3(64, 4),  256, 0, stream>>>(Wi1, Wp1, 1280, 0);
    k_pack<<<dim3(64, 16), 256, 0, stream>>>(Wh1, Wp1, 1280, 256);
    k_pack<<<dim3(64, 16), 256, 0, stream>>>(Wi2, Wp2, 2048, 0);
    k_pack<<<dim3(64, 16), 256, 0, stream>>>(Wh2, Wp2, 2048, 1024);
    k_prep<<<512, 256, 0, stream>>>(bi1, bh1, bi2, bh2, h01, h02, b1, b2, h1r, h2b, cnt);

    k_persist<<<256, 256, 0, stream>>>(Wp1, Wp2, xall, h1r, h2b, h2f, b1, b2, c01, c02, cnt);

    k_final<<<128, 64, 0, stream>>>(h2f, Wc, bc, y);
}